// Round 1
// baseline (408.004 us; speedup 1.0000x reference)
//
#include <hip/hip_runtime.h>

#define NKER  128
#define INDIM 1024
#define UNITS 1024

typedef __attribute__((ext_vector_type(8)))  short          bf16x8;
typedef __attribute__((ext_vector_type(4)))  float          f32x4;
typedef __attribute__((ext_vector_type(4)))  unsigned short u16x4;
typedef __attribute__((ext_vector_type(8)))  unsigned short u16x8;

__device__ __forceinline__ unsigned short f2bf(float f) {
    // RNE fp32 -> bf16 via native conversion
    return __builtin_bit_cast(unsigned short, static_cast<__bf16>(f));
}

// swizzled LDS element index for (row r, k in 0..31), 16B-unit XOR swizzle
__device__ __forceinline__ int swzidx(int r, int k) {
    return r * 32 + ((((k >> 3) ^ ((r >> 1) & 3)) << 3) | (k & 7));
}

__global__ void __launch_bounds__(256, 2)
dense_local(const float* __restrict__ X, const float* __restrict__ Kn,
            float* __restrict__ Out)
{
    __shared__ __align__(16) unsigned short lA[2][128 * 32];
    __shared__ __align__(16) unsigned short lB[2][128 * 32];

    // XCD-aware swizzle: 4096 wgs, 512 per XCD, k-major within an XCD chunk
    const int bid  = blockIdx.x;
    const int wg   = (bid & 7) * 512 + (bid >> 3);
    const int kidx = wg >> 5;          // 0..127
    const int tile = wg & 31;
    const int mt   = tile >> 3;        // 0..3  (M tiles of 128 over 512)
    const int nt   = tile & 7;         // 0..7  (N tiles of 128 over 1024)

    const int t  = threadIdx.x;
    const int l  = t & 63;
    const int w  = t >> 6;
    const int wr = w >> 1, wc = w & 1; // wave quadrant of the 128x128 tile
    const int l15 = l & 15, g = l >> 4;

    const size_t MROW = (size_t)NKER * INDIM; // 131072: row stride of x and out

    const float* Abase = X  + (size_t)mt * 128 * MROW + (size_t)kidx * INDIM;
    const float* Bbase = Kn + (size_t)kidx * INDIM * UNITS + nt * 128;
    float*       Cbase = Out + (size_t)mt * 128 * MROW + (size_t)kidx * UNITS + nt * 128;

    // staging thread maps
    const int ar0 = t >> 3;            // A: rows 0..31 (+p*32)
    const int akq = (t & 7) << 2;      // A: k quad 0,4,...,28
    const int bn  = ((w & 1) << 6) | l;// B: column 0..127 (lane-consecutive!)
    const int bkh = w >> 1;            // B: k half 0..1

    f32x4 acc[4][4];
#pragma unroll
    for (int mi = 0; mi < 4; ++mi)
#pragma unroll
        for (int ni = 0; ni < 4; ++ni)
            acc[mi][ni] = f32x4{0.f, 0.f, 0.f, 0.f};

    f32x4 av[4];
    float bv[16];

    auto loadg = [&](int kc) {
#pragma unroll
        for (int p = 0; p < 4; ++p)
            av[p] = *(const f32x4*)(Abase + (size_t)(ar0 + p * 32) * MROW + kc + akq);
        const float* bp = Bbase + (size_t)(kc + bkh * 16) * UNITS + bn;
#pragma unroll
        for (int j = 0; j < 16; ++j)
            bv[j] = bp[(size_t)j * UNITS];   // coalesced: 64 consecutive lanes = 256B
    };

    auto writes = [&](int bb) {
#pragma unroll
        for (int p = 0; p < 4; ++p) {
            const int row = ar0 + p * 32;
            u16x4 h;
#pragma unroll
            for (int c = 0; c < 4; ++c) h[c] = f2bf(av[p][c]);
            *(u16x4*)&lA[bb][swzidx(row, akq)] = h;
        }
        u16x8 h0, h1;
#pragma unroll
        for (int j = 0; j < 8; ++j) { h0[j] = f2bf(bv[j]); h1[j] = f2bf(bv[j + 8]); }
        *(u16x8*)&lB[bb][swzidx(bn, bkh * 16)]     = h0;  // transpose happens here:
        *(u16x8*)&lB[bb][swzidx(bn, bkh * 16 + 8)] = h1;  // row = n, k-contiguous
    };

    auto compute = [&](int bb) {
        bf16x8 af[4], bfr[4];
#pragma unroll
        for (int mi = 0; mi < 4; ++mi) {
            const int r = wr * 64 + mi * 16 + l15;
            af[mi] = *(const bf16x8*)&lA[bb][swzidx(r, g * 8)];
        }
#pragma unroll
        for (int ni = 0; ni < 4; ++ni) {
            const int r = wc * 64 + ni * 16 + l15;
            bfr[ni] = *(const bf16x8*)&lB[bb][swzidx(r, g * 8)];
        }
#pragma unroll
        for (int mi = 0; mi < 4; ++mi)
#pragma unroll
            for (int ni = 0; ni < 4; ++ni)
                acc[mi][ni] = __builtin_amdgcn_mfma_f32_16x16x32_bf16(
                    af[mi], bfr[ni], acc[mi][ni], 0, 0, 0);
    };

    loadg(0);
    writes(0);
    __syncthreads();

    int bb = 0;
#pragma unroll 1
    for (int step = 0; step < 32; ++step) {
        if (step < 31) loadg((step + 1) * 32);  // issue next-tile loads early
        compute(bb);
        __syncthreads();
        if (step < 31) writes(bb ^ 1);
        __syncthreads();
        bb ^= 1;
    }

    // epilogue: softplus + store (C/D layout: col=lane&15, row=(lane>>4)*4+reg)
#pragma unroll
    for (int mi = 0; mi < 4; ++mi) {
#pragma unroll
        for (int ni = 0; ni < 4; ++ni) {
            const int n = wc * 64 + ni * 16 + l15;
#pragma unroll
            for (int r = 0; r < 4; ++r) {
                const int m = wr * 64 + mi * 16 + g * 4 + r;
                const float v  = acc[mi][ni][r];
                const float sp = fmaxf(v, 0.0f) + log1pf(__expf(-fabsf(v)));
                Cbase[(size_t)m * MROW + n] = sp;
            }
        }
    }
}

extern "C" void kernel_launch(void* const* d_in, const int* in_sizes, int n_in,
                              void* d_out, int out_size, void* d_ws, size_t ws_size,
                              hipStream_t stream) {
    const float* X  = (const float*)d_in[0];
    const float* Kn = (const float*)d_in[1];
    float* O = (float*)d_out;
    dense_local<<<4096, 256, 0, stream>>>(X, Kn, O);
}

// Round 2
// 407.282 us; speedup vs baseline: 1.0018x; 1.0018x over previous
//
#include <hip/hip_runtime.h>

#define NKER  128
#define INDIM 1024
#define UNITS 1024

typedef __attribute__((ext_vector_type(8)))  short          bf16x8;
typedef __attribute__((ext_vector_type(4)))  float          f32x4;
typedef __attribute__((ext_vector_type(4)))  unsigned short u16x4;
typedef __attribute__((ext_vector_type(8)))  unsigned short u16x8;

__device__ __forceinline__ unsigned short f2bf(float f) {
    // RNE fp32 -> bf16
    return __builtin_bit_cast(unsigned short, static_cast<__bf16>(f));
}

// swizzled LDS element index for (row r, k in 0..31), 16B-unit XOR swizzle
// verified conflict-free (round 1: SQ_LDS_BANK_CONFLICT == 0)
__device__ __forceinline__ int swzidx(int r, int k) {
    return r * 32 + ((((k >> 3) ^ ((r >> 1) & 3)) << 3) | (k & 7));
}

__global__ void __launch_bounds__(512, 2)
dense_local(const float* __restrict__ X, const float* __restrict__ Kn,
            float* __restrict__ Out)
{
    __shared__ __align__(16) unsigned short lA[2][256 * 32];  // 32 KB total
    __shared__ __align__(16) unsigned short lB[2][128 * 32];  // 16 KB total

    // XCD swizzle: 2048 wgs, 256/XCD, k-major inside an XCD chunk (bijective)
    const int bid  = blockIdx.x;
    const int wg   = (bid & 7) * 256 + (bid >> 3);
    const int kidx = wg >> 4;          // 0..127
    const int tile = wg & 15;
    const int mt   = tile >> 3;        // 0..1  (M tiles of 256 over 512)
    const int nt   = tile & 7;         // 0..7  (N tiles of 128 over 1024)

    const int t   = threadIdx.x;
    const int l   = t & 63;
    const int w   = t >> 6;            // 0..7
    const int wm  = w >> 1;            // 0..3  wave m-quadrant (64 rows each)
    const int wn  = w & 1;             // 0..1  wave n-half (64 cols each)
    const int l15 = l & 15, g = l >> 4;

    const size_t MROW = (size_t)NKER * INDIM; // 131072: row stride of x / out

    const float* Abase = X   + (size_t)mt * 256 * MROW + (size_t)kidx * INDIM;
    const float* Bbase = Kn  + (size_t)kidx * INDIM * UNITS + nt * 128;
    float*       Cbase = Out + (size_t)mt * 256 * MROW + (size_t)kidx * UNITS + nt * 128;

    // staging maps
    const int ar0 = t >> 3;            // A: rows 0..63 (+p*64)
    const int ak4 = (t & 7) << 2;      // A: k quad 0,4,...,28
    const int bn  = t & 127;           // B: column 0..127 (lane-consecutive)
    const int bkh = t >> 7;            // B: k-octet 0..3

    f32x4 acc[4][4];
#pragma unroll
    for (int mi = 0; mi < 4; ++mi)
#pragma unroll
        for (int ni = 0; ni < 4; ++ni)
            acc[mi][ni] = f32x4{0.f, 0.f, 0.f, 0.f};

    f32x4 av[4];
    float bv[8];

    auto loadg = [&](int kc) {
#pragma unroll
        for (int p = 0; p < 4; ++p)
            av[p] = *(const f32x4*)(Abase + (size_t)(ar0 + p * 64) * MROW + kc + ak4);
        const float* bp = Bbase + (size_t)(kc + bkh * 8) * UNITS + bn;
#pragma unroll
        for (int j = 0; j < 8; ++j)
            bv[j] = bp[(size_t)j * UNITS];   // 64 consecutive lanes = 256B coalesced
    };

    auto writes = [&](int bb) {
#pragma unroll
        for (int p = 0; p < 4; ++p) {
            u16x4 h;
#pragma unroll
            for (int c = 0; c < 4; ++c) h[c] = f2bf(av[p][c]);
            *(u16x4*)&lA[bb][swzidx(ar0 + p * 64, ak4)] = h;
        }
        u16x8 h0;
#pragma unroll
        for (int j = 0; j < 8; ++j) h0[j] = f2bf(bv[j]);
        // transpose happens here: row = n, k-contiguous, one packed b128 write
        *(u16x8*)&lB[bb][swzidx(bn, bkh * 8)] = h0;
    };

    auto compute = [&](int bb) {
        bf16x8 af[4], bfr[4];
#pragma unroll
        for (int mi = 0; mi < 4; ++mi) {
            const int r = wm * 64 + mi * 16 + l15;
            af[mi] = *(const bf16x8*)&lA[bb][swzidx(r, g * 8)];
        }
#pragma unroll
        for (int ni = 0; ni < 4; ++ni) {
            const int r = wn * 64 + ni * 16 + l15;
            bfr[ni] = *(const bf16x8*)&lB[bb][swzidx(r, g * 8)];
        }
#pragma unroll
        for (int mi = 0; mi < 4; ++mi)
#pragma unroll
            for (int ni = 0; ni < 4; ++ni)
                acc[mi][ni] = __builtin_amdgcn_mfma_f32_16x16x32_bf16(
                    af[mi], bfr[ni], acc[mi][ni], 0, 0, 0);
    };

    loadg(0);
    writes(0);
    __syncthreads();

    int bb = 0;
#pragma unroll 1
    for (int step = 0; step < 32; ++step) {
        if (step < 31) loadg((step + 1) * 32);  // issue next-tile loads early
        compute(bb);
        __syncthreads();
        if (step < 31) writes(bb ^ 1);
        __syncthreads();
        bb ^= 1;
    }

    // epilogue: softplus + store (C/D layout: col=lane&15, row=(lane>>4)*4+reg)
#pragma unroll
    for (int mi = 0; mi < 4; ++mi) {
#pragma unroll
        for (int ni = 0; ni < 4; ++ni) {
            const int n = wn * 64 + ni * 16 + l15;
#pragma unroll
            for (int r = 0; r < 4; ++r) {
                const int m = wm * 64 + mi * 16 + g * 4 + r;
                const float v  = acc[mi][ni][r];
                const float sp = fmaxf(v, 0.0f) + log1pf(__expf(-fabsf(v)));
                Cbase[(size_t)m * MROW + n] = sp;
            }
        }
    }
}

extern "C" void kernel_launch(void* const* d_in, const int* in_sizes, int n_in,
                              void* d_out, int out_size, void* d_ws, size_t ws_size,
                              hipStream_t stream) {
    const float* X  = (const float*)d_in[0];
    const float* Kn = (const float*)d_in[1];
    float* O = (float*)d_out;
    dense_local<<<2048, 512, 0, stream>>>(X, Kn, O);
}